// Round 9
// baseline (23.699 us; speedup 1.0000x reference)
//
#include <hip/hip_runtime.h>
#include <stdint.h>

// Shapes fixed by setup_inputs: B=4, D=20, H=W=128, HW=16384, 1024 tiles of 64 voxels.
// 512 blocks x 2 tiles, double-buffered LDS stage (pred 60ch + cmask 20ch per tile),
// gt (dst points) in registers (30 coalesced loads/tile, issued up-front).
// Counted s_waitcnt vmcnt(35) + raw s_barrier keep tile-B's loads in flight
// across tile-A compute (T3/T4: don't drain vmcnt to 0 mid-pipeline).
// Per-wave vm-op ledger: 36 scalars+gtA | 5 stageA | 30 gtB | 5 stageB = 76;
// vmcnt(35) <=> scalars+gtA+stageA complete. Finalize: R7-proven separate
// 1-wave kernel over the 1024 records (no atomics, no OOB: ws use = 32 KB).
#define HW      16384
#define NBLOCKS 512
#define NTILES  1024

// smem float offsets
#define STG0   0        // tile buf 0: pred ch0..59 at ch*64, cmask c at (60+c)*64
#define STG1   5120     // tile buf 1
#define RMMo   10240    // row-min(sel): [row 0..19][cj 0..1][64]
#define D2So   12800    // col-min:      [col 0..19][ri 0..1][64]
#define MXo    15360    // [wave 0..3][64]
#define SMEM_F 15616    // 62464 B -> 2 blocks/CU

#define MEMBAR()  asm volatile("" ::: "memory")
#define WAITV35() asm volatile("s_waitcnt vmcnt(35)" ::: "memory")
#define WAITV0()  asm volatile("s_waitcnt vmcnt(0)" ::: "memory")
#define WAITL0()  asm volatile("s_waitcnt lgkmcnt(0)" ::: "memory")
#define SBAR() do { __builtin_amdgcn_sched_barrier(0); __builtin_amdgcn_s_barrier(); \
                    __builtin_amdgcn_sched_barrier(0); } while (0)

__device__ __forceinline__ void gload_lds16(const float* g, float* l) {
    __builtin_amdgcn_global_load_lds(
        (const __attribute__((address_space(1))) uint32_t*)g,
        (__attribute__((address_space(3))) uint32_t*)l, 16, 0, 0);
}

// 5 async staging instrs per wave (20 total = 80 channels x 64 voxels)
__device__ __forceinline__ void stage_tile(float* smem, int stg, int lane, int w,
                                           const float* pb, const float* cb)
{
    const int sub = lane >> 4;           // channel-within-quad
    const int vo  = (lane & 15) * 4;     // 4 consecutive voxels per lane
    #pragma unroll
    for (int q = 0; q < 5; ++q) {
        const int t   = w + q * 4;       // 0..19
        const int ch0 = t * 4;
        const float* src = (ch0 < 60) ? (pb + (size_t)(ch0 + sub) * HW + vo)
                                      : (cb + (size_t)(ch0 - 60 + sub) * HW + vo);
        gload_lds16(src, &smem[stg + ch0 * 64]);
    }
}

__device__ __forceinline__ void compute_tile(float* smem, int stg, int lane,
    int w, int ri, int cj,
    const float (&dx)[10], const float (&dy)[10], const float (&dz)[10],
    unsigned& cmbits_out)
{
    const int j0 = cj * 10, i0 = ri * 10;
    unsigned cmbits = 0u;
    #pragma unroll
    for (int j = 0; j < 20; ++j)
        if (smem[stg + (60 + j) * 64 + lane] > 0.f) cmbits |= 1u << j;
    // row-min column selection: masked cols if any masked (globally), else all
    const unsigned sel = cmbits ? ((cmbits >> j0) & 0x3FFu) : 0x3FFu;

    const float INF = __int_as_float(0x7f800000);
    float rmm[10], d2s[10], mx = 0.f;
    #pragma unroll
    for (int t = 0; t < 10; ++t) { rmm[t] = INF; d2s[t] = INF; }

    #pragma unroll
    for (int r = 0; r < 10; ++r) {
        const int i = i0 + r;
        const float sx = smem[stg + (i)      * 64 + lane];
        const float sy = smem[stg + (20 + i) * 64 + lane];
        const float sz = smem[stg + (40 + i) * 64 + lane];
        #pragma unroll
        for (int jj = 0; jj < 10; ++jj) {
            float d = fabsf(sx - dx[jj]) + fabsf(sy - dy[jj]) + fabsf(sz - dz[jj]);
            mx      = fmaxf(mx, d);
            d2s[jj] = fminf(d2s[jj], d);
            rmm[r]  = fminf(rmm[r], ((sel >> jj) & 1u) ? d : INF);
        }
    }
    #pragma unroll
    for (int t = 0; t < 10; ++t) {
        smem[RMMo + ((i0 + t) * 2 + cj) * 64 + lane] = rmm[t];
        smem[D2So + ((j0 + t) * 2 + ri) * 64 + lane] = d2s[t];
    }
    smem[MXo + w * 64 + lane] = mx;
    cmbits_out = cmbits;
}

// wave 0 only: per-voxel combine + wave reduce + record store
__device__ __forceinline__ void finalize_tile(const float* smem, int lane,
    unsigned cmbits, float vw, float pn, float gn, float* rec)
{
    float srcA = 0.f;
    #pragma unroll
    for (int i = 0; i < 20; ++i)
        srcA += fminf(smem[RMMo + (i * 2)     * 64 + lane],
                      smem[RMMo + (i * 2 + 1) * 64 + lane]);
    float dsum = 0.f;
    #pragma unroll
    for (int j = 0; j < 20; ++j) {
        float m = fminf(smem[D2So + (j * 2)     * 64 + lane],
                        smem[D2So + (j * 2 + 1) * 64 + lane]);
        if ((cmbits >> j) & 1u) dsum += m;
    }
    float mx = fmaxf(fmaxf(smem[MXo + lane],       smem[MXo + 64 + lane]),
                     fmaxf(smem[MXo + 128 + lane], smem[MXo + 192 + lane]));

    float vals[7];
    vals[0] = srcA * vw;                          // src-loss min-sum
    vals[1] = (cmbits == 0u) ? 20.f * vw : 0.f;   // rows needing +max_d
    vals[2] = dsum * vw;                          // dst-loss numerator
    vals[3] = vw * (float)__popc(cmbits);         // dst-loss denominator
    const float diff = pn - gn;
    const float ad = fabsf(diff);
    vals[4] = ((ad < 1.f) ? 0.5f * diff * diff : (ad - 0.5f)) * vw;
    vals[5] = vw;                                 // wsum
    vals[6] = (vw > 0.f) ? mx : 0.f;              // masked max

    #pragma unroll
    for (int o = 32; o > 0; o >>= 1) {
        #pragma unroll
        for (int x = 0; x < 6; ++x) vals[x] += __shfl_down(vals[x], o);
        vals[6] = fmaxf(vals[6], __shfl_down(vals[6], o));
    }
    if (lane == 0) {
        #pragma unroll
        for (int x = 0; x < 7; ++x) rec[x] = vals[x];
    }
}

__global__ __launch_bounds__(256, 2) void chamfer_main(
    const float* __restrict__ pred,   // [B, 60, HW]  channel c*20+i
    const float* __restrict__ gt,     // [B, 60, HW]  channel j*3+c
    const float* __restrict__ cmask,  // [B, 20, HW]
    const float* __restrict__ vmask,  // [B, HW]
    const float* __restrict__ pnum,   // [B, HW]
    const float* __restrict__ gnum,   // [B, HW]
    float* __restrict__ ws)
{
    __shared__ float smem[SMEM_F];
    const int tid  = threadIdx.x;
    const int lane = tid & 63;
    const int w    = tid >> 6;
    const int ri   = w >> 1;
    const int cj   = w & 1;
    const int j0   = cj * 10;

    const int tA = blockIdx.x, tB = blockIdx.x + NBLOCKS;
    const int kA = tA * 64, kB = tB * 64;
    const int bA = kA >> 14, hwA = kA & (HW - 1);
    const int bB = kB >> 14, hwB = kB & (HW - 1);
    const float* pbA = pred  + (size_t)bA * 60 * HW + hwA;
    const float* tbA = gt    + (size_t)bA * 60 * HW + hwA;
    const float* cbA = cmask + (size_t)bA * 20 * HW + hwA;
    const float* pbB = pred  + (size_t)bB * 60 * HW + hwB;
    const float* tbB = gt    + (size_t)bB * 60 * HW + hwB;
    const float* cbB = cmask + (size_t)bB * 20 * HW + hwB;

    // ---- group 1 (36 vm ops): finalize scalars + gt regs for tile A
    const float vwA = vmask[kA + lane], pnA = pnum[kA + lane], gnA = gnum[kA + lane];
    const float vwB = vmask[kB + lane], pnB = pnum[kB + lane], gnB = gnum[kB + lane];
    float dxa[10], dya[10], dza[10];
    #pragma unroll
    for (int jj = 0; jj < 10; ++jj) {
        dxa[jj] = tbA[(size_t)(3 * (j0 + jj)    ) * HW + lane];
        dya[jj] = tbA[(size_t)(3 * (j0 + jj) + 1) * HW + lane];
        dza[jj] = tbA[(size_t)(3 * (j0 + jj) + 2) * HW + lane];
    }
    MEMBAR();
    // ---- group 2 (5): stage tile A
    stage_tile(smem, STG0, lane, w, pbA, cbA);
    MEMBAR();
    // ---- group 3 (30): gt regs for tile B
    float dxb[10], dyb[10], dzb[10];
    #pragma unroll
    for (int jj = 0; jj < 10; ++jj) {
        dxb[jj] = tbB[(size_t)(3 * (j0 + jj)    ) * HW + lane];
        dyb[jj] = tbB[(size_t)(3 * (j0 + jj) + 1) * HW + lane];
        dzb[jj] = tbB[(size_t)(3 * (j0 + jj) + 2) * HW + lane];
    }
    MEMBAR();
    // ---- group 4 (5): stage tile B
    stage_tile(smem, STG1, lane, w, pbB, cbB);

    // tile A ready when only groups 3+4 (30+5=35) may be outstanding
    WAITV35();
    SBAR();

    unsigned cmA;
    compute_tile(smem, STG0, lane, w, ri, cj, dxa, dya, dza, cmA);
    WAITL0();
    SBAR();
    if (w == 0) finalize_tile(smem, lane, cmA, vwA, pnA, gnA, ws + (size_t)tA * 8);

    // tile B data ready AND wave-0 finalize done before partials overwritten
    WAITV0();
    SBAR();

    unsigned cmB;
    compute_tile(smem, STG1, lane, w, ri, cj, dxb, dyb, dzb, cmB);
    WAITL0();
    SBAR();
    if (w == 0) finalize_tile(smem, lane, cmB, vwB, pnB, gnB, ws + (size_t)tB * 8);
}

__global__ __launch_bounds__(64) void chamfer_fin(
    const float* __restrict__ ws, float* __restrict__ out)
{
    const int t = threadIdx.x;   // one wave: 64 lanes x 16 records
    float a[6] = {0.f, 0.f, 0.f, 0.f, 0.f, 0.f};
    float mx = 0.f;
    for (int r = t; r < NTILES; r += 64) {
        const float* rec = ws + (size_t)r * 8;
        #pragma unroll
        for (int v = 0; v < 6; ++v) a[v] += rec[v];
        mx = fmaxf(mx, rec[6]);
    }
    #pragma unroll
    for (int o = 32; o > 0; o >>= 1) {
        #pragma unroll
        for (int v = 0; v < 6; ++v) a[v] += __shfl_down(a[v], o);
        mx = fmaxf(mx, __shfl_down(mx, o));
    }
    if (t == 0) {
        const float loss_s = (a[0] + a[1] * mx) / (a[5] * 20.f);
        const float loss_d = a[2] / a[3];
        const float numl   = a[4] / a[5];
        out[0] = loss_s + loss_d + 0.1f * numl;
    }
}

extern "C" void kernel_launch(void* const* d_in, const int* in_sizes, int n_in,
                              void* d_out, int out_size, void* d_ws, size_t ws_size,
                              hipStream_t stream)
{
    const float* pred  = (const float*)d_in[0];
    const float* gt    = (const float*)d_in[1];
    const float* cmask = (const float*)d_in[2];
    const float* vmask = (const float*)d_in[3];
    const float* pnum  = (const float*)d_in[4];
    const float* gnum  = (const float*)d_in[5];
    float* out = (float*)d_out;
    float* ws  = (float*)d_ws;

    chamfer_main<<<NBLOCKS, 256, 0, stream>>>(pred, gt, cmask, vmask, pnum, gnum, ws);
    chamfer_fin<<<1, 64, 0, stream>>>(ws, out);
}

// Round 11
// 18.278 us; speedup vs baseline: 1.2966x; 1.2966x over previous
//
#include <hip/hip_runtime.h>
#include <stdint.h>

// Shapes fixed by setup_inputs: B=4, D=20, H=W=128, HW=16384, 1024 tiles of 64 voxels.
// R10/R11: direct-load design (R4 structure, whose 98us was ~90us contended-atomic
// tail, not compute). Block = 64 voxels x 8 waves; wave (ri,cj) owns rows
// ri*10..+9 x cols cj*5..+4. All loads are direct coalesced 256B global loads
// (independent -> deep MLP, no stage barriers). Cross-wave combine via LDS
// int atomicMin/Max (non-negative floats: int order == float order). Finalize
// stores per-tile records (R7-proven, zero contended atomics); 256-thread fin.
#define HW     16384
#define NTILES 1024
#define INFI   0x7f800000

__global__ __launch_bounds__(512, 6) void chamfer_main(
    const float* __restrict__ pred,   // [B, 60, HW]  channel c*20+i
    const float* __restrict__ gt,     // [B, 60, HW]  channel j*3+c
    const float* __restrict__ cmask,  // [B, 20, HW]
    const float* __restrict__ vmask,  // [B, HW]
    const float* __restrict__ pnum,   // [B, HW]
    const float* __restrict__ gnum,   // [B, HW]
    float* __restrict__ ws)
{
    __shared__ int rm_m[20][64];   // per-row masked min  (float bits)
    __shared__ int rm_a[20][64];   // per-row all min
    __shared__ int cd_s[20][64];   // per-col min (d2s)
    __shared__ int mx_s[64];       // per-voxel max dist
    __shared__ int bt_s[64];       // per-voxel cmask bits

    const int tid  = threadIdx.x;
    const int lane = tid & 63;     // voxel within tile
    const int w    = tid >> 6;     // wave 0..7
    const int ri   = w >> 2;       // 0..1 -> rows i0..i0+9
    const int cj   = w & 3;        // 0..3 -> cols j0..j0+4
    const int i0   = ri * 10, j0 = cj * 5;
    const int k    = blockIdx.x * 64 + lane;
    const int b    = k >> 14;
    const int hw   = k & (HW - 1);
    const size_t pb = (size_t)b * 60 * HW + hw;
    const size_t cb = (size_t)b * 20 * HW + hw;

    // ---- issue independent global loads up-front (each 64-lane x 4B = 256B coalesced)
    float dxv[5], dyv[5], dzv[5], cmf[5];
    #pragma unroll
    for (int jj = 0; jj < 5; ++jj) {
        dxv[jj] = gt[pb + (size_t)(3 * (j0 + jj)    ) * HW];
        dyv[jj] = gt[pb + (size_t)(3 * (j0 + jj) + 1) * HW];
        dzv[jj] = gt[pb + (size_t)(3 * (j0 + jj) + 2) * HW];
        cmf[jj] = cmask[cb + (size_t)(j0 + jj) * HW];
    }
    float vw = 0.f, pn = 0.f, gn = 0.f;
    if (w == 0) { vw = vmask[k]; pn = pnum[k]; gn = gnum[k]; }

    // ---- init LDS while loads are in flight
    {
        int* pm = &rm_m[0][0]; int* pa = &rm_a[0][0]; int* pc = &cd_s[0][0];
        for (int t = tid; t < 1280; t += 512) { pm[t] = INFI; pa[t] = INFI; pc[t] = INFI; }
        if (tid < 64) { mx_s[tid] = 0; bt_s[tid] = 0; }
    }
    __syncthreads();

    unsigned mybits = 0u;
    #pragma unroll
    for (int jj = 0; jj < 5; ++jj)
        if (cmf[jj] > 0.f) mybits |= 1u << jj;
    if (ri == 0 && mybits) atomicOr(&bt_s[lane], (int)(mybits << j0));

    const float INF = __int_as_float(INFI);
    float rmm[10], rma[10], cds[5], mx = 0.f;
    #pragma unroll
    for (int t = 0; t < 10; ++t) { rmm[t] = INF; rma[t] = INF; }
    #pragma unroll
    for (int t = 0; t < 5; ++t) cds[t] = INF;

    #pragma unroll
    for (int r = 0; r < 10; ++r) {
        const int i = i0 + r;
        const float sx = pred[pb + (size_t)(i)      * HW];
        const float sy = pred[pb + (size_t)(20 + i) * HW];
        const float sz = pred[pb + (size_t)(40 + i) * HW];
        #pragma unroll
        for (int jj = 0; jj < 5; ++jj) {
            float d = fabsf(sx - dxv[jj]) + fabsf(sy - dyv[jj]) + fabsf(sz - dzv[jj]);
            mx      = fmaxf(mx, d);
            cds[jj] = fminf(cds[jj], d);
            rma[r]  = fminf(rma[r], d);
            rmm[r]  = fminf(rmm[r], (cmf[jj] > 0.f) ? d : INF);  // cmp hoisted to 5 masks
        }
    }

    // ---- cross-wave combine: int atomics (all values >= 0 -> int order == float order)
    #pragma unroll
    for (int r = 0; r < 10; ++r) {
        atomicMin(&rm_m[i0 + r][lane], __float_as_int(rmm[r]));
        atomicMin(&rm_a[i0 + r][lane], __float_as_int(rma[r]));
    }
    #pragma unroll
    for (int jj = 0; jj < 5; ++jj)
        atomicMin(&cd_s[j0 + jj][lane], __float_as_int(cds[jj]));
    atomicMax(&mx_s[lane], __float_as_int(mx));
    __syncthreads();

    // ---- finalize: wave 0, lane = voxel
    if (w == 0) {
        const unsigned cmbits = (unsigned)bt_s[lane];
        float srcA = 0.f;
        #pragma unroll
        for (int i = 0; i < 20; ++i) {
            const int vm_ = rm_m[i][lane];
            const int va_ = rm_a[i][lane];
            srcA += __int_as_float(cmbits ? vm_ : va_);   // masked min, else all-min (+maxd later)
        }
        float dsum = 0.f;
        #pragma unroll
        for (int j = 0; j < 20; ++j)
            if ((cmbits >> j) & 1u) dsum += __int_as_float(cd_s[j][lane]);
        const float mxv = __int_as_float(mx_s[lane]);

        float vals[7];
        vals[0] = srcA * vw;                          // src-loss min-sum
        vals[1] = (cmbits == 0u) ? 20.f * vw : 0.f;   // rows needing +max_d
        vals[2] = dsum * vw;                          // dst-loss numerator
        vals[3] = vw * (float)__popc(cmbits);         // dst-loss denominator
        const float diff = pn - gn;
        const float ad = fabsf(diff);
        vals[4] = ((ad < 1.f) ? 0.5f * diff * diff : (ad - 0.5f)) * vw;
        vals[5] = vw;                                 // wsum
        vals[6] = (vw > 0.f) ? mxv : 0.f;             // masked max

        #pragma unroll
        for (int o = 32; o > 0; o >>= 1) {
            #pragma unroll
            for (int x = 0; x < 6; ++x) vals[x] += __shfl_down(vals[x], o);
            vals[6] = fmaxf(vals[6], __shfl_down(vals[6], o));
        }
        if (lane == 0) {
            float* rec = ws + (size_t)blockIdx.x * 8;
            #pragma unroll
            for (int x = 0; x < 7; ++x) rec[x] = vals[x];
        }
    }
}

__global__ __launch_bounds__(256) void chamfer_fin(
    const float* __restrict__ ws, float* __restrict__ out)
{
    __shared__ float red[4][8];
    const int tid  = threadIdx.x;
    const int lane = tid & 63;
    const int wv   = tid >> 6;
    float a[6] = {0.f, 0.f, 0.f, 0.f, 0.f, 0.f};
    float mx = 0.f;
    for (int r = tid; r < NTILES; r += 256) {
        const float* rec = ws + (size_t)r * 8;
        #pragma unroll
        for (int v = 0; v < 6; ++v) a[v] += rec[v];
        mx = fmaxf(mx, rec[6]);
    }
    #pragma unroll
    for (int o = 32; o > 0; o >>= 1) {
        #pragma unroll
        for (int v = 0; v < 6; ++v) a[v] += __shfl_down(a[v], o);
        mx = fmaxf(mx, __shfl_down(mx, o));
    }
    if (lane == 0) {
        #pragma unroll
        for (int v = 0; v < 6; ++v) red[wv][v] = a[v];
        red[wv][6] = mx;
    }
    __syncthreads();
    if (tid == 0) {
        #pragma unroll
        for (int v = 0; v < 6; ++v) a[v] = red[0][v] + red[1][v] + red[2][v] + red[3][v];
        mx = fmaxf(fmaxf(red[0][6], red[1][6]), fmaxf(red[2][6], red[3][6]));
        const float loss_s = (a[0] + a[1] * mx) / (a[5] * 20.f);
        const float loss_d = a[2] / a[3];
        const float numl   = a[4] / a[5];
        out[0] = loss_s + loss_d + 0.1f * numl;
    }
}

extern "C" void kernel_launch(void* const* d_in, const int* in_sizes, int n_in,
                              void* d_out, int out_size, void* d_ws, size_t ws_size,
                              hipStream_t stream)
{
    const float* pred  = (const float*)d_in[0];
    const float* gt    = (const float*)d_in[1];
    const float* cmask = (const float*)d_in[2];
    const float* vmask = (const float*)d_in[3];
    const float* pnum  = (const float*)d_in[4];
    const float* gnum  = (const float*)d_in[5];
    float* out = (float*)d_out;
    float* ws  = (float*)d_ws;

    chamfer_main<<<NTILES, 512, 0, stream>>>(pred, gt, cmask, vmask, pnum, gnum, ws);
    chamfer_fin<<<1, 256, 0, stream>>>(ws, out);
}